// Round 5
// baseline (292.980 us; speedup 1.0000x reference)
//
#include <hip/hip_runtime.h>
#include <hip/hip_bf16.h>
#include <hip/hip_fp16.h>

// GAT layer on MI355X (gfx950).
//   x: (N=50000, K=256) fp32, W: (K=256, F=64) fp32, a: (1, 128) fp32
//   edge_index: (2, E=1600000) int (src row 0, dst row 1)
// out = elu( segsum_src(e * h[dst]) / segsum_src(e) ),
//   e = exp(-leakyrelu(s_src[src]+s_dst[dst], 0.2)), h = x@W
//
// Round 5:
//  - bin pass merged (hist+scan+scatter in one kernel, per-block-private
//    output regions, zero global atomics); bhist/bscan kernels deleted.
//  - bsort computes the edge weight (exp) and emits packed u32 =
//    dst | f16(wgt)<<16; gather loses the exp + random s_dst stream and
//    does a single u32 load per edge.

#define ALPHA 0.2f
#define KDIM 256
#define FDIM 64
#define BIN_CHUNK 8192
#define BUCKET_CAP 16384   // max edges per 256-src bucket (mean ~8163)
#define OFFW 257           // per-block offset table row width

typedef __bf16 bf16x8 __attribute__((ext_vector_type(8)));
typedef float f32x4 __attribute__((ext_vector_type(4)));
typedef unsigned int u32;
typedef unsigned short u16;

// ---------------------------------------------------------------------------
// Kernel 0: w_t[n][k] = bf16(W[k][n])   (64 x 256 bf16 = 32 KB, L1-resident)
// ---------------------------------------------------------------------------
__global__ __launch_bounds__(256) void gat_wt_kernel(
    const float* __restrict__ W, __hip_bfloat16* __restrict__ w_t)
{
    const int t = blockIdx.x * 256 + threadIdx.x;
    if (t < KDIM * FDIM) {
        const int k = t >> 6;
        const int n = t & 63;
        w_t[n * KDIM + k] = __float2bfloat16(W[t]);
    }
}

// ---------------------------------------------------------------------------
// Kernel 1: h = bf16(x @ W) via mfma_f32_16x16x32_bf16, scores fp32.
// (unchanged from round 3/4)
// ---------------------------------------------------------------------------
__global__ __launch_bounds__(256) void gat_gemm_kernel(
    const float* __restrict__ x, const __hip_bfloat16* __restrict__ w_tp,
    const float* __restrict__ a, __hip_bfloat16* __restrict__ h_bf,
    float* __restrict__ s_src, float* __restrict__ s_dst, int N)
{
    const int lane = threadIdx.x & 63;
    const int wv = threadIdx.x >> 6;
    const int m0 = blockIdx.x * 64 + wv * 16;
    const int c = lane & 15;
    const int q = lane >> 4;

    const int mrow = m0 + c;
    const float* xp = x + (long)(mrow < N ? mrow : N - 1) * KDIM;
    const __bf16* wt = (const __bf16*)w_tp;

    f32x4 acc[4];
#pragma unroll
    for (int ct = 0; ct < 4; ++ct) acc[ct] = (f32x4){0.f, 0.f, 0.f, 0.f};

#pragma unroll 2
    for (int kc = 0; kc < 8; ++kc) {
        const int k0 = kc * 32 + q * 8;
        const float4 xa = *(const float4*)(xp + k0);
        const float4 xb = *(const float4*)(xp + k0 + 4);
        bf16x8 af;
        af[0] = (__bf16)xa.x; af[1] = (__bf16)xa.y;
        af[2] = (__bf16)xa.z; af[3] = (__bf16)xa.w;
        af[4] = (__bf16)xb.x; af[5] = (__bf16)xb.y;
        af[6] = (__bf16)xb.z; af[7] = (__bf16)xb.w;
#pragma unroll
        for (int ct = 0; ct < 4; ++ct) {
            const bf16x8 bf = *(const bf16x8*)(wt + (ct * 16 + c) * KDIM + k0);
            acc[ct] = __builtin_amdgcn_mfma_f32_16x16x32_bf16(af, bf, acc[ct], 0, 0, 0);
        }
    }

    float a1c[4], a2c[4];
#pragma unroll
    for (int ct = 0; ct < 4; ++ct) {
        a1c[ct] = a[ct * 16 + c];
        a2c[ct] = a[FDIM + ct * 16 + c];
    }
    float s1r[4], s2r[4];
#pragma unroll
    for (int reg = 0; reg < 4; ++reg) {
        float s1 = 0.f, s2 = 0.f;
#pragma unroll
        for (int ct = 0; ct < 4; ++ct) {
            s1 += acc[ct][reg] * a1c[ct];
            s2 += acc[ct][reg] * a2c[ct];
        }
        s1r[reg] = s1; s2r[reg] = s2;
    }
#pragma unroll
    for (int off = 1; off < 16; off <<= 1) {
#pragma unroll
        for (int reg = 0; reg < 4; ++reg) {
            s1r[reg] += __shfl_xor(s1r[reg], off);
            s2r[reg] += __shfl_xor(s2r[reg], off);
        }
    }

#pragma unroll
    for (int reg = 0; reg < 4; ++reg) {
        const int row = m0 + q * 4 + reg;
        if (row < N) {
#pragma unroll
            for (int ct = 0; ct < 4; ++ct)
                h_bf[(long)row * FDIM + ct * 16 + c] = __float2bfloat16(acc[ct][reg]);
            if (c == 0) { s_src[row] = s1r[reg]; s_dst[row] = s2r[reg]; }
        }
    }
}

// ---------------------------------------------------------------------------
// Kernel 2: single-pass bin. Per-block local hist + scan (no global atomics),
// scatter packed (srclo<<16)|dst into the block's private region of pair[],
// grouped by bucket. Writes per-block exclusive offsets off_blk[blk][0..256].
// ---------------------------------------------------------------------------
__global__ __launch_bounds__(256) void gat_bin_kernel(
    const int* __restrict__ srcA, const int* __restrict__ dstA,
    int* __restrict__ off_blk, u32* __restrict__ pair, int E)
{
    __shared__ int hist[256];
    __shared__ int cur[256];
    __shared__ int wsum[4];
    const int t = threadIdx.x;
    const int lane = t & 63;
    const int w = t >> 6;
    const int base = blockIdx.x * BIN_CHUNK;
    const int cnt = min(BIN_CHUNK, E - base);

    hist[t] = 0;
    __syncthreads();
    for (int i = t; i < cnt; i += 256) atomicAdd(&hist[srcA[base + i] >> 8], 1);
    __syncthreads();

    const int v = hist[t];
    int incl = v;
#pragma unroll
    for (int off = 1; off < 64; off <<= 1) {
        const int nv = __shfl_up(incl, off);
        if (lane >= off) incl += nv;
    }
    if (lane == 63) wsum[w] = incl;
    __syncthreads();
    int woff = 0;
    if (w > 0) woff += wsum[0];
    if (w > 1) woff += wsum[1];
    if (w > 2) woff += wsum[2];
    const int excl = woff + incl - v;
    off_blk[blockIdx.x * OFFW + t] = excl;
    if (t == 0) off_blk[blockIdx.x * OFFW + 256] = cnt;
    cur[t] = excl;
    __syncthreads();

    for (int i = t; i < cnt; i += 256) {
        const int s = srcA[base + i];
        const int d = dstA[base + i];
        const int pos = atomicAdd(&cur[s >> 8], 1);
        pair[base + pos] = ((u32)(s & 255) << 16) | (u32)d;   // d < 65536
    }
}

// ---------------------------------------------------------------------------
// Kernel 3: bucket bases. totals[b] = sum over blocks of run length; scan.
// One block of 256 threads.
// ---------------------------------------------------------------------------
__global__ __launch_bounds__(256) void gat_bbase_kernel(
    const int* __restrict__ off_blk, int* __restrict__ bbase, int NBLK)
{
    __shared__ int wsum[4];
    const int t = threadIdx.x;
    const int lane = t & 63;
    const int w = t >> 6;
    int total = 0;
    for (int blk = 0; blk < NBLK; ++blk) {
        const int* ob = off_blk + blk * OFFW;
        total += ob[t + 1] - ob[t];
    }
    int incl = total;
#pragma unroll
    for (int off = 1; off < 64; off <<= 1) {
        const int nv = __shfl_up(incl, off);
        if (lane >= off) incl += nv;
    }
    if (lane == 63) wsum[w] = incl;
    __syncthreads();
    int woff = 0;
    if (w > 0) woff += wsum[0];
    if (w > 1) woff += wsum[1];
    if (w > 2) woff += wsum[2];
    const int excl = woff + incl - total;
    bbase[t] = excl;
    if (t == 255) bbase[256] = excl + total;   // = E
}

// ---------------------------------------------------------------------------
// Kernel 4: per-bucket LDS counting sort + weight computation.
// One block per bucket. Emits offs[] (CSR) and sorted_pk = dst | f16(wgt)<<16.
// ---------------------------------------------------------------------------
__global__ __launch_bounds__(256) void gat_bsort_kernel(
    const u32* __restrict__ pair, const int* __restrict__ off_blk,
    const int* __restrict__ bbase, const float* __restrict__ s_src,
    const float* __restrict__ s_dst, int* __restrict__ offs,
    u32* __restrict__ sorted_pk, int N, int NBLK, int NB)
{
    __shared__ u32 chunk[BUCKET_CAP];   // 64 KB
    __shared__ int cur[256];
    __shared__ float ssl[256];
    __shared__ int wsum[4];

    const int b = blockIdx.x;
    const int t = threadIdx.x;
    const int lane = t & 63;
    const int w = t >> 6;
    const int e0 = bbase[b];
    const int e1 = bbase[b + 1];
    const int n = min(e1 - e0, BUCKET_CAP);

    // gather this bucket's runs from all block-private regions
    int pos = 0;
    for (int blk = 0; blk < NBLK; ++blk) {
        const int s = off_blk[blk * OFFW + b];
        const int c = off_blk[blk * OFFW + b + 1] - s;
        const u32* pp = pair + blk * BIN_CHUNK + s;
        for (int i = t; i < c; i += 256) {
            const int dp = pos + i;
            if (dp < BUCKET_CAP) chunk[dp] = pp[i];
        }
        pos += c;
    }
    cur[t] = 0;
    ssl[t] = (b * 256 + t < N) ? s_src[b * 256 + t] : 0.f;
    __syncthreads();

    // per-src histogram
    for (int i = t; i < n; i += 256) atomicAdd(&cur[chunk[i] >> 16], 1);
    __syncthreads();

    // exclusive scan of 256 per-src counts
    const int v = cur[t];
    int incl = v;
#pragma unroll
    for (int off = 1; off < 64; off <<= 1) {
        const int nv = __shfl_up(incl, off);
        if (lane >= off) incl += nv;
    }
    if (lane == 63) wsum[w] = incl;
    __syncthreads();
    int woff = 0;
    if (w > 0) woff += wsum[0];
    if (w > 1) woff += wsum[1];
    if (w > 2) woff += wsum[2];
    const int excl = woff + incl - v;
    if (b * 256 + t < N) offs[b * 256 + t] = e0 + excl;
    if (b == NB - 1 && t == 0) offs[N] = e1;
    __syncthreads();
    cur[t] = excl;
    __syncthreads();

    // scatter: compute weight, pack, write direct to global (32 KB window)
    for (int i = t; i < n; i += 256) {
        const u32 p = chunk[i];
        const int sl = p >> 16;
        const int d = (int)(p & 0xFFFFu);
        const int slot = atomicAdd(&cur[sl], 1);
        const float sc = ssl[sl] + s_dst[d];
        const float lr = sc > 0.f ? sc : ALPHA * sc;
        const float wgt = __expf(-lr);
        const u32 wh = (u32)__half_as_ushort(__float2half(wgt));
        sorted_pk[e0 + slot] = (u32)d | (wh << 16);
    }
}

// ---------------------------------------------------------------------------
// Kernel 5: segmented reduction over bf16 h. One wave per node, 8 edge slots
// x 8 feature octets. One packed u32 load per edge; no exp/score here.
// ---------------------------------------------------------------------------
__global__ __launch_bounds__(256) void gat_gather_kernel(
    const int* __restrict__ offs, const u32* __restrict__ sorted_pk,
    const __hip_bfloat16* __restrict__ h_bf, float* __restrict__ out, int N)
{
    const int node = blockIdx.x * 4 + (threadIdx.x >> 6);
    if (node >= N) return;
    const int lane = threadIdx.x & 63;
    const int q = lane >> 3;   // edge slot 0..7
    const int c = lane & 7;    // feature octet 0..7

    const int start = offs[node];
    const int end = offs[node + 1];
    const __bf16* hb = (const __bf16*)h_bf;

    float acc[8];
#pragma unroll
    for (int j = 0; j < 8; ++j) acc[j] = 0.f;
    float wsum = 0.f;

#pragma unroll 2
    for (int e = start + q; e < end; e += 8) {
        const u32 p = sorted_pk[e];
        const float wgt = __half2float(__ushort_as_half((u16)(p >> 16)));
        const int d = (int)(p & 0xFFFFu);
        const bf16x8 hv = *(const bf16x8*)(hb + (long)d * FDIM + 8 * c);
#pragma unroll
        for (int j = 0; j < 8; ++j) acc[j] += wgt * (float)hv[j];
        wsum += wgt;
    }

#pragma unroll
    for (int off = 8; off < 64; off <<= 1) {
#pragma unroll
        for (int j = 0; j < 8; ++j) acc[j] += __shfl_xor(acc[j], off);
        wsum += __shfl_xor(wsum, off);
    }

    if (q == 0) {
        const float inv = 1.0f / wsum;
        float o[8];
#pragma unroll
        for (int j = 0; j < 8; ++j) {
            const float v = acc[j] * inv;
            o[j] = v > 0.f ? v : expm1f(v);
        }
        float* op = &out[(long)node * FDIM + 8 * c];
        *(float4*)op = make_float4(o[0], o[1], o[2], o[3]);
        *(float4*)(op + 4) = make_float4(o[4], o[5], o[6], o[7]);
    }
}

extern "C" void kernel_launch(void* const* d_in, const int* in_sizes, int n_in,
                              void* d_out, int out_size, void* d_ws, size_t ws_size,
                              hipStream_t stream) {
    const float* x = (const float*)d_in[0];
    const float* W = (const float*)d_in[1];
    const float* a = (const float*)d_in[2];
    const int* ei  = (const int*)d_in[3];

    const int N = in_sizes[0] / KDIM;       // 50000
    const int E = in_sizes[3] / 2;          // 1600000
    const int NB = (N + 255) >> 8;          // 196 buckets
    const int NBLK = (E + BIN_CHUNK - 1) / BIN_CHUNK;  // 196 bin blocks
    const int* srcA = ei;
    const int* dstA = ei + E;

    // workspace layout (all regions 16B aligned; total ~20 MB)
    __hip_bfloat16* h_bf = (__hip_bfloat16*)d_ws;          // N*64 bf16
    __hip_bfloat16* w_t  = h_bf + (size_t)N * FDIM;        // 64*256 bf16
    float* s_src = (float*)(w_t + KDIM * FDIM);            // N
    float* s_dst = s_src + N;                              // N
    int* offs    = (int*)(s_dst + N);                      // N+1 (pad N+4)
    int* off_blk = offs + N + 4;                           // NBLK*OFFW
    int* bbase   = off_blk + NBLK * OFFW;                  // 257 (pad 260)
    u32* pair    = (u32*)(bbase + 260);                    // E
    u32* sorted_pk = pair + E;                             // E
    float* out   = (float*)d_out;

    gat_wt_kernel<<<dim3((KDIM * FDIM + 255) / 256), dim3(256), 0, stream>>>(W, w_t);
    gat_gemm_kernel<<<dim3((N + 63) / 64), dim3(256), 0, stream>>>(
        x, w_t, a, h_bf, s_src, s_dst, N);

    gat_bin_kernel<<<dim3(NBLK), dim3(256), 0, stream>>>(srcA, dstA, off_blk, pair, E);
    gat_bbase_kernel<<<dim3(1), dim3(256), 0, stream>>>(off_blk, bbase, NBLK);
    gat_bsort_kernel<<<dim3(NB), dim3(256), 0, stream>>>(
        pair, off_blk, bbase, s_src, s_dst, offs, sorted_pk, N, NBLK, NB);

    gat_gather_kernel<<<dim3((N + 3) / 4), dim3(256), 0, stream>>>(
        offs, sorted_pk, h_bf, out, N);
}

// Round 6
// 210.762 us; speedup vs baseline: 1.3901x; 1.3901x over previous
//
#include <hip/hip_runtime.h>
#include <hip/hip_bf16.h>
#include <hip/hip_fp16.h>

// GAT layer on MI355X (gfx950).
//   x: (N=50000, K=256) fp32, W: (K=256, F=64) fp32, a: (1, 128) fp32
//   edge_index: (2, E=1600000) int (src row 0, dst row 1)
// out = elu( segsum_src(e * h[dst]) / segsum_src(e) ),
//   e = exp(-leakyrelu(s_src[src]+s_dst[dst], 0.2)), h = x@W
//
// Round 6: undo round-5's block-private pair regions (they made bsort's load
// a 196-iteration serial gather: 97us at 1.8% VALUBusy). Back to bucket-
// contiguous pair[] via global reservation atomics, and shrink buckets to
// 64 srcs (782 blocks, 16KB LDS) for occupancy. Keep round-5's wgt-packing
// in bsort and the slim gather.

#define ALPHA 0.2f
#define KDIM 256
#define FDIM 64
#define BIN_CHUNK 8192
#define BUCKET_CAP 4096    // 64-src bucket: mean ~2046 edges, cap is >40 sigma

typedef __bf16 bf16x8 __attribute__((ext_vector_type(8)));
typedef float f32x4 __attribute__((ext_vector_type(4)));
typedef unsigned int u32;
typedef unsigned short u16;

// ---------------------------------------------------------------------------
// Kernel 0: w_t[n][k] = bf16(W[k][n])   (64 x 256 bf16 = 32 KB, L1-resident)
// ---------------------------------------------------------------------------
__global__ __launch_bounds__(256) void gat_wt_kernel(
    const float* __restrict__ W, __hip_bfloat16* __restrict__ w_t)
{
    const int t = blockIdx.x * 256 + threadIdx.x;
    if (t < KDIM * FDIM) {
        const int k = t >> 6;
        const int n = t & 63;
        w_t[n * KDIM + k] = __float2bfloat16(W[t]);
    }
}

// ---------------------------------------------------------------------------
// Kernel 1: h = bf16(x @ W) via mfma_f32_16x16x32_bf16, scores fp32.
// (unchanged since round 3)
// ---------------------------------------------------------------------------
__global__ __launch_bounds__(256) void gat_gemm_kernel(
    const float* __restrict__ x, const __hip_bfloat16* __restrict__ w_tp,
    const float* __restrict__ a, __hip_bfloat16* __restrict__ h_bf,
    float* __restrict__ s_src, float* __restrict__ s_dst, int N)
{
    const int lane = threadIdx.x & 63;
    const int wv = threadIdx.x >> 6;
    const int m0 = blockIdx.x * 64 + wv * 16;
    const int c = lane & 15;
    const int q = lane >> 4;

    const int mrow = m0 + c;
    const float* xp = x + (long)(mrow < N ? mrow : N - 1) * KDIM;
    const __bf16* wt = (const __bf16*)w_tp;

    f32x4 acc[4];
#pragma unroll
    for (int ct = 0; ct < 4; ++ct) acc[ct] = (f32x4){0.f, 0.f, 0.f, 0.f};

#pragma unroll 2
    for (int kc = 0; kc < 8; ++kc) {
        const int k0 = kc * 32 + q * 8;
        const float4 xa = *(const float4*)(xp + k0);
        const float4 xb = *(const float4*)(xp + k0 + 4);
        bf16x8 af;
        af[0] = (__bf16)xa.x; af[1] = (__bf16)xa.y;
        af[2] = (__bf16)xa.z; af[3] = (__bf16)xa.w;
        af[4] = (__bf16)xb.x; af[5] = (__bf16)xb.y;
        af[6] = (__bf16)xb.z; af[7] = (__bf16)xb.w;
#pragma unroll
        for (int ct = 0; ct < 4; ++ct) {
            const bf16x8 bf = *(const bf16x8*)(wt + (ct * 16 + c) * KDIM + k0);
            acc[ct] = __builtin_amdgcn_mfma_f32_16x16x32_bf16(af, bf, acc[ct], 0, 0, 0);
        }
    }

    float a1c[4], a2c[4];
#pragma unroll
    for (int ct = 0; ct < 4; ++ct) {
        a1c[ct] = a[ct * 16 + c];
        a2c[ct] = a[FDIM + ct * 16 + c];
    }
    float s1r[4], s2r[4];
#pragma unroll
    for (int reg = 0; reg < 4; ++reg) {
        float s1 = 0.f, s2 = 0.f;
#pragma unroll
        for (int ct = 0; ct < 4; ++ct) {
            s1 += acc[ct][reg] * a1c[ct];
            s2 += acc[ct][reg] * a2c[ct];
        }
        s1r[reg] = s1; s2r[reg] = s2;
    }
#pragma unroll
    for (int off = 1; off < 16; off <<= 1) {
#pragma unroll
        for (int reg = 0; reg < 4; ++reg) {
            s1r[reg] += __shfl_xor(s1r[reg], off);
            s2r[reg] += __shfl_xor(s2r[reg], off);
        }
    }

#pragma unroll
    for (int reg = 0; reg < 4; ++reg) {
        const int row = m0 + q * 4 + reg;
        if (row < N) {
#pragma unroll
            for (int ct = 0; ct < 4; ++ct)
                h_bf[(long)row * FDIM + ct * 16 + c] = __float2bfloat16(acc[ct][reg]);
            if (c == 0) { s_src[row] = s1r[reg]; s_dst[row] = s2r[reg]; }
        }
    }
}

// ---------------------------------------------------------------------------
// Kernel 2: bucket histogram (bucket = src>>6), LDS-aggregated.
// ---------------------------------------------------------------------------
__global__ __launch_bounds__(256) void gat_bhist_kernel(
    const int* __restrict__ srcA, int* __restrict__ bcnt, int E, int NBU)
{
    __shared__ int hist[1024];
    const int t = threadIdx.x;
    for (int j = t; j < 1024; j += 256) hist[j] = 0;
    __syncthreads();
    const int base = blockIdx.x * BIN_CHUNK;
    const int cnt = min(BIN_CHUNK, E - base);
    for (int i = t; i < cnt; i += 256)
        atomicAdd(&hist[srcA[base + i] >> 6], 1);
    __syncthreads();
    for (int j = t; j < NBU; j += 256) {
        const int v = hist[j];
        if (v) atomicAdd(&bcnt[j], v);
    }
}

// ---------------------------------------------------------------------------
// Kernel 3: exclusive scan of 1024 (padded) bucket counts -> bbase, bcur.
// Single block, 4 elements/thread.
// ---------------------------------------------------------------------------
__global__ __launch_bounds__(256) void gat_bscan_kernel(
    const int* __restrict__ bcnt, int* __restrict__ bbase, int* __restrict__ bcur)
{
    __shared__ int wsum[4];
    const int t = threadIdx.x;
    const int lane = t & 63;
    const int w = t >> 6;
    const int4 v = *(const int4*)&bcnt[4 * t];   // padded region is zero
    const int tsum = v.x + v.y + v.z + v.w;
    int incl = tsum;
#pragma unroll
    for (int off = 1; off < 64; off <<= 1) {
        const int nv = __shfl_up(incl, off);
        if (lane >= off) incl += nv;
    }
    if (lane == 63) wsum[w] = incl;
    __syncthreads();
    int woff = 0;
    if (w > 0) woff += wsum[0];
    if (w > 1) woff += wsum[1];
    if (w > 2) woff += wsum[2];
    const int e0 = woff + incl - tsum;
    const int4 o = make_int4(e0, e0 + v.x, e0 + v.x + v.y, e0 + v.x + v.y + v.z);
    *(int4*)&bbase[4 * t] = o;
    *(int4*)&bcur[4 * t] = o;
    if (t == 255) bbase[1024] = e0 + tsum;   // = E
}

// ---------------------------------------------------------------------------
// Kernel 4: bin. Local hist, one global reservation atomic per (block,bucket),
// then scatter packed (srclo<<16)|dst into bucket-contiguous pair[] at the
// reserved (contiguous) run. src/dst re-read from L2.
// ---------------------------------------------------------------------------
__global__ __launch_bounds__(256) void gat_bin_kernel(
    const int* __restrict__ srcA, const int* __restrict__ dstA,
    int* __restrict__ bcur, u32* __restrict__ pair, int E, int NBU)
{
    __shared__ int hist[1024];
    __shared__ int lcur[1024];
    const int t = threadIdx.x;
    for (int j = t; j < 1024; j += 256) hist[j] = 0;
    __syncthreads();
    const int base = blockIdx.x * BIN_CHUNK;
    const int cnt = min(BIN_CHUNK, E - base);
    for (int i = t; i < cnt; i += 256)
        atomicAdd(&hist[srcA[base + i] >> 6], 1);
    __syncthreads();
    for (int j = t; j < NBU; j += 256) {
        const int v = hist[j];
        lcur[j] = v ? atomicAdd(&bcur[j], v) : 0;
    }
    __syncthreads();
    for (int i = t; i < cnt; i += 256) {
        const int s = srcA[base + i];
        const int d = dstA[base + i];
        const int pos = atomicAdd(&lcur[s >> 6], 1);
        pair[pos] = ((u32)(s & 63) << 16) | (u32)d;   // d < 65536
    }
}

// ---------------------------------------------------------------------------
// Kernel 5: per-bucket LDS counting sort + weight pack. One block per 64-src
// bucket (16 KB LDS). Contiguous load, single-wave scan, emits offs[] (CSR)
// and sorted_pk = dst | f16(wgt)<<16.
// ---------------------------------------------------------------------------
__global__ __launch_bounds__(256) void gat_bsort_kernel(
    const u32* __restrict__ pair, const int* __restrict__ bbase,
    const float* __restrict__ s_src, const float* __restrict__ s_dst,
    int* __restrict__ offs, u32* __restrict__ sorted_pk, int N, int NBU)
{
    __shared__ u32 chunk[BUCKET_CAP];   // 16 KB
    __shared__ int cur[64];
    __shared__ float ssl[64];

    const int b = blockIdx.x;
    const int t = threadIdx.x;
    const int s0 = b << 6;
    const int e0 = bbase[b];
    const int e1 = bbase[b + 1];
    const int n = min(e1 - e0, BUCKET_CAP);

    if (t < 64) {
        cur[t] = 0;
        ssl[t] = (s0 + t < N) ? s_src[s0 + t] : 0.f;
    }
    __syncthreads();
    for (int i = t; i < n; i += 256) {
        const u32 p = pair[e0 + i];
        chunk[i] = p;
        atomicAdd(&cur[p >> 16], 1);
    }
    __syncthreads();
    if (t < 64) {   // wave 0: exclusive scan of 64 counts
        const int v = cur[t];
        int incl = v;
#pragma unroll
        for (int off = 1; off < 64; off <<= 1) {
            const int nv = __shfl_up(incl, off);
            if (t >= off) incl += nv;
        }
        const int excl = incl - v;
        if (s0 + t < N) offs[s0 + t] = e0 + excl;
        cur[t] = excl;
    }
    if (b == NBU - 1 && t == 0) offs[N] = e1;
    __syncthreads();
    for (int i = t; i < n; i += 256) {
        const u32 p = chunk[i];
        const int sl = p >> 16;
        const int d = (int)(p & 0xFFFFu);
        const int slot = atomicAdd(&cur[sl], 1);
        const float sc = ssl[sl] + s_dst[d];
        const float lr = sc > 0.f ? sc : ALPHA * sc;
        const float wgt = __expf(-lr);
        const u32 wh = (u32)__half_as_ushort(__float2half(wgt));
        sorted_pk[e0 + slot] = (u32)d | (wh << 16);
    }
}

// ---------------------------------------------------------------------------
// Kernel 6: segmented reduction over bf16 h. One wave per node, 8 edge slots
// x 8 feature octets. One packed u32 load per edge. (unchanged from round 5)
// ---------------------------------------------------------------------------
__global__ __launch_bounds__(256) void gat_gather_kernel(
    const int* __restrict__ offs, const u32* __restrict__ sorted_pk,
    const __hip_bfloat16* __restrict__ h_bf, float* __restrict__ out, int N)
{
    const int node = blockIdx.x * 4 + (threadIdx.x >> 6);
    if (node >= N) return;
    const int lane = threadIdx.x & 63;
    const int q = lane >> 3;   // edge slot 0..7
    const int c = lane & 7;    // feature octet 0..7

    const int start = offs[node];
    const int end = offs[node + 1];
    const __bf16* hb = (const __bf16*)h_bf;

    float acc[8];
#pragma unroll
    for (int j = 0; j < 8; ++j) acc[j] = 0.f;
    float wsum = 0.f;

#pragma unroll 2
    for (int e = start + q; e < end; e += 8) {
        const u32 p = sorted_pk[e];
        const float wgt = __half2float(__ushort_as_half((u16)(p >> 16)));
        const int d = (int)(p & 0xFFFFu);
        const bf16x8 hv = *(const bf16x8*)(hb + (long)d * FDIM + 8 * c);
#pragma unroll
        for (int j = 0; j < 8; ++j) acc[j] += wgt * (float)hv[j];
        wsum += wgt;
    }

#pragma unroll
    for (int off = 8; off < 64; off <<= 1) {
#pragma unroll
        for (int j = 0; j < 8; ++j) acc[j] += __shfl_xor(acc[j], off);
        wsum += __shfl_xor(wsum, off);
    }

    if (q == 0) {
        const float inv = 1.0f / wsum;
        float o[8];
#pragma unroll
        for (int j = 0; j < 8; ++j) {
            const float v = acc[j] * inv;
            o[j] = v > 0.f ? v : expm1f(v);
        }
        float* op = &out[(long)node * FDIM + 8 * c];
        *(float4*)op = make_float4(o[0], o[1], o[2], o[3]);
        *(float4*)(op + 4) = make_float4(o[4], o[5], o[6], o[7]);
    }
}

extern "C" void kernel_launch(void* const* d_in, const int* in_sizes, int n_in,
                              void* d_out, int out_size, void* d_ws, size_t ws_size,
                              hipStream_t stream) {
    const float* x = (const float*)d_in[0];
    const float* W = (const float*)d_in[1];
    const float* a = (const float*)d_in[2];
    const int* ei  = (const int*)d_in[3];

    const int N = in_sizes[0] / KDIM;       // 50000
    const int E = in_sizes[3] / 2;          // 1600000
    const int NBU = (N + 63) >> 6;          // 782 buckets of 64 srcs
    const int NBLK = (E + BIN_CHUNK - 1) / BIN_CHUNK;  // 196 chunks
    const int* srcA = ei;
    const int* dstA = ei + E;

    // workspace layout (all regions 16B aligned; total ~20 MB)
    __hip_bfloat16* h_bf = (__hip_bfloat16*)d_ws;          // N*64 bf16
    __hip_bfloat16* w_t  = h_bf + (size_t)N * FDIM;        // 64*256 bf16
    float* s_src = (float*)(w_t + KDIM * FDIM);            // N
    float* s_dst = s_src + N;                              // N
    int* offs    = (int*)(s_dst + N);                      // N+1 (pad N+4)
    int* bcnt    = offs + N + 4;                           // 1024 (zeroed)
    int* bbase   = bcnt + 1024;                            // 1025 (pad 1028)
    int* bcur    = bbase + 1028;                           // 1024
    u32* pair    = (u32*)(bcur + 1024);                    // E
    u32* sorted_pk = pair + E;                             // E
    float* out   = (float*)d_out;

    hipMemsetAsync(bcnt, 0, 1024 * sizeof(int), stream);

    gat_wt_kernel<<<dim3((KDIM * FDIM + 255) / 256), dim3(256), 0, stream>>>(W, w_t);
    gat_gemm_kernel<<<dim3((N + 63) / 64), dim3(256), 0, stream>>>(
        x, w_t, a, h_bf, s_src, s_dst, N);

    gat_bhist_kernel<<<dim3(NBLK), dim3(256), 0, stream>>>(srcA, bcnt, E, NBU);
    gat_bscan_kernel<<<dim3(1), dim3(256), 0, stream>>>(bcnt, bbase, bcur);
    gat_bin_kernel<<<dim3(NBLK), dim3(256), 0, stream>>>(srcA, dstA, bcur, pair, E, NBU);
    gat_bsort_kernel<<<dim3(NBU), dim3(256), 0, stream>>>(
        pair, bbase, s_src, s_dst, offs, sorted_pk, N, NBU);

    gat_gather_kernel<<<dim3((N + 3) / 4), dim3(256), 0, stream>>>(
        offs, sorted_pk, h_bf, out, N);
}